// Round 6
// baseline (319.242 us; speedup 1.0000x reference)
//
#include <hip/hip_runtime.h>
#include <hip/hip_cooperative_groups.h>

// FEM stiffness matrix assembly (negated): out = -M, dense N x N (N = 9216).
//
// R6: single cooperative dispatch.
//   phase 1: branchless flat grid-stride nontemporal zero of the whole
//            340 MB output (same access pattern as the rocclr fill kernel
//            that profiles at ~86% of HBM peak)
//   grid.sync()
//   phase 2: atomic scatter of the 9 contributions per triangle
//            (q = w / T keeps the contribution-switch wave-uniform)
// Removes the second launch and the full inter-dispatch drain of the
// memset+scatter structure (R1/R5, 68.3-68.6 us). The measured dur_us
// directly reveals the achievable zero bandwidth (dur ~ zero + ~6 us).

namespace cg = cooperative_groups;

typedef float f32x4 __attribute__((ext_vector_type(4)));

__device__ __forceinline__ void tri_values(const float* __restrict__ pts,
                                           const int* __restrict__ cmap,
                                           int t, int nd[3], float M[6]) {
    int ni = cmap[3 * t + 0];
    int nj = cmap[3 * t + 1];
    int nk = cmap[3 * t + 2];
    nd[0] = ni; nd[1] = nj; nd[2] = nk;

    float x0 = pts[2 * ni + 0], y0 = pts[2 * ni + 1];
    float x1 = pts[2 * nj + 0], y1 = pts[2 * nj + 1];
    float x2 = pts[2 * nk + 0], y2 = pts[2 * nk + 1];

    float det = (x1 - x0) * (y2 - y0) - (x2 - x0) * (y1 - y0);
    float area = 0.5f * fabsf(det);
    float inv = 1.0f / det;

    float gix = (y1 - y2) * inv, giy = (x2 - x1) * inv;
    float gjx = (y2 - y0) * inv, gjy = (x0 - x2) * inv;
    float gkx = (y0 - y1) * inv, gky = (x1 - x0) * inv;

    M[0] = (gix * gix + giy * giy) * area;  // ii
    M[1] = (gjx * gjx + gjy * gjy) * area;  // jj
    M[2] = (gkx * gkx + gky * gky) * area;  // kk
    M[3] = (gix * gjx + giy * gjy) * area;  // ij
    M[4] = (gjx * gkx + gjy * gky) * area;  // jk
    M[5] = (gkx * gix + gky * giy) * area;  // ki
}

__global__ void __launch_bounds__(256) fused_zero_scatter_kernel(
        const float* __restrict__ pts,
        const int* __restrict__ cmap,
        float* __restrict__ out,
        int T, int N) {
    // ---- phase 1: branchless NT zero of the dense output ----
    size_t nvec = ((size_t)N * N) >> 2;
    f32x4* __restrict__ o4 = (f32x4*)out;
    const f32x4 z = (f32x4){0.f, 0.f, 0.f, 0.f};
    size_t stride = (size_t)gridDim.x * blockDim.x;
    for (size_t v = (size_t)blockIdx.x * blockDim.x + threadIdx.x; v < nvec; v += stride) {
        __builtin_nontemporal_store(z, &o4[v]);
    }

    cg::this_grid().sync();

    // ---- phase 2: atomic scatter (grid-stride over 9*T work items) ----
    size_t total = (size_t)9 * T;
    for (size_t w = (size_t)blockIdx.x * blockDim.x + threadIdx.x; w < total; w += stride) {
        int q = (int)(w / (size_t)T);   // wave-uniform except at T boundaries
        int t = (int)(w - (size_t)q * T);

        int nd[3]; float M[6];
        tri_values(pts, cmap, t, nd, M);

        int row, col; float val;
        switch (q) {
            case 0: row = nd[0]; col = nd[0]; val = M[0]; break;  // ii
            case 1: row = nd[1]; col = nd[1]; val = M[1]; break;  // jj
            case 2: row = nd[2]; col = nd[2]; val = M[2]; break;  // kk
            case 3: row = nd[0]; col = nd[1]; val = M[3]; break;  // ij
            case 4: row = nd[1]; col = nd[0]; val = M[3]; break;  // ji
            case 5: row = nd[1]; col = nd[2]; val = M[4]; break;  // jk
            case 6: row = nd[2]; col = nd[1]; val = M[4]; break;  // kj
            case 7: row = nd[2]; col = nd[0]; val = M[5]; break;  // ki
            default: row = nd[0]; col = nd[2]; val = M[5]; break; // ik
        }
        atomicAdd(&out[(size_t)row * N + col], -val);
    }
}

// ---- Fallback (if cooperative launch is rejected): memset + scatter ----
__global__ void scatter_out_kernel(const float* __restrict__ pts,
                                   const int* __restrict__ cmap,
                                   float* __restrict__ out,
                                   int T, int N) {
    int t = blockIdx.x * blockDim.x + threadIdx.x;
    if (t >= T) return;
    int q = blockIdx.y;
    int nd[3]; float M[6];
    tri_values(pts, cmap, t, nd, M);
    int row, col; float val;
    switch (q) {
        case 0: row = nd[0]; col = nd[0]; val = M[0]; break;
        case 1: row = nd[1]; col = nd[1]; val = M[1]; break;
        case 2: row = nd[2]; col = nd[2]; val = M[2]; break;
        case 3: row = nd[0]; col = nd[1]; val = M[3]; break;
        case 4: row = nd[1]; col = nd[0]; val = M[3]; break;
        case 5: row = nd[1]; col = nd[2]; val = M[4]; break;
        case 6: row = nd[2]; col = nd[1]; val = M[4]; break;
        case 7: row = nd[2]; col = nd[0]; val = M[5]; break;
        default: row = nd[0]; col = nd[2]; val = M[5]; break;
    }
    atomicAdd(&out[(size_t)row * N + col], -val);
}

extern "C" void kernel_launch(void* const* d_in, const int* in_sizes, int n_in,
                              void* d_out, int out_size, void* d_ws, size_t ws_size,
                              hipStream_t stream) {
    const float* pts = (const float*)d_in[0];   // (N, 2) float32
    const int* cmap = (const int*)d_in[1];      // (T, 3) int
    int N = in_sizes[0] / 2;                    // 9216 nodes
    int T = in_sizes[1] / 3;                    // 18050 triangles
    float* out = (float*)d_out;

    // Co-resident grid: query occupancy (pure host call, graph-safe),
    // clamp to [1, 8] blocks/CU on 256 CUs.
    int occ = 0;
    (void)hipOccupancyMaxActiveBlocksPerMultiprocessor(&occ, fused_zero_scatter_kernel, 256, 0);
    if (occ < 1) occ = 1;
    if (occ > 8) occ = 8;
    int grid = occ * 256;  // MI355X: 256 CUs

    void* args[] = {(void*)&pts, (void*)&cmap, (void*)&out, (void*)&T, (void*)&N};
    hipError_t err = hipLaunchCooperativeKernel((void*)fused_zero_scatter_kernel,
                                                dim3(grid), dim3(256), args, 0, stream);
    if (err != hipSuccess) {
        // Deterministic fallback: two-pass memset + atomic scatter (R5 path).
        (void)hipMemsetAsync(d_out, 0, (size_t)out_size * sizeof(float), stream);
        dim3 sgrid((T + 255) / 256, 9);
        scatter_out_kernel<<<sgrid, 256, 0, stream>>>(pts, cmap, out, T, N);
    }
}

// Round 7
// 75.540 us; speedup vs baseline: 4.2261x; 4.2261x over previous
//
#include <hip/hip_runtime.h>

// FEM stiffness matrix assembly (negated): out = -M, dense N x N (N = 9216).
//
// R7: custom zero kernel (PLAIN stores — R6 proved nontemporal stores bypass
// L2 write-combining on gfx950: FETCH_SIZE showed 4x the output size in
// partial-line RMW reads, ~1 TB/s) + 9-way-parallel atomic scatter.
//
// Zero kernel: flat lane-interleaved grid stride, 1536 blocks x 256 threads
// = 393,216 threads; 9216^2/4 = 21,233,664 f32x4 vectors = exactly 54 per
// thread (no tail). Plain stores allocate in L2 and write back full lines.

typedef float f32x4 __attribute__((ext_vector_type(4)));

__global__ void __launch_bounds__(256) zero_kernel(float* __restrict__ out,
                                                   size_t nvec) {
    f32x4* __restrict__ o4 = (f32x4*)out;
    const f32x4 z = (f32x4){0.f, 0.f, 0.f, 0.f};
    size_t stride = (size_t)gridDim.x * blockDim.x;
    size_t v = (size_t)blockIdx.x * blockDim.x + threadIdx.x;
    // Main unrolled loop: 6 independent stores per iteration for MLP.
    size_t bound6 = nvec > 5 * stride ? nvec - 5 * stride : 0;
    for (; v < bound6; v += 6 * stride) {
        o4[v] = z;
        o4[v + stride] = z;
        o4[v + 2 * stride] = z;
        o4[v + 3 * stride] = z;
        o4[v + 4 * stride] = z;
        o4[v + 5 * stride] = z;
    }
    for (; v < nvec; v += stride) o4[v] = z;
}

__device__ __forceinline__ void tri_values(const float* __restrict__ pts,
                                           const int* __restrict__ cmap,
                                           int t, int nd[3], float M[6]) {
    int ni = cmap[3 * t + 0];
    int nj = cmap[3 * t + 1];
    int nk = cmap[3 * t + 2];
    nd[0] = ni; nd[1] = nj; nd[2] = nk;

    float x0 = pts[2 * ni + 0], y0 = pts[2 * ni + 1];
    float x1 = pts[2 * nj + 0], y1 = pts[2 * nj + 1];
    float x2 = pts[2 * nk + 0], y2 = pts[2 * nk + 1];

    float det = (x1 - x0) * (y2 - y0) - (x2 - x0) * (y1 - y0);
    float area = 0.5f * fabsf(det);
    float inv = 1.0f / det;

    float gix = (y1 - y2) * inv, giy = (x2 - x1) * inv;
    float gjx = (y2 - y0) * inv, gjy = (x0 - x2) * inv;
    float gkx = (y0 - y1) * inv, gky = (x1 - x0) * inv;

    M[0] = (gix * gix + giy * giy) * area;  // ii
    M[1] = (gjx * gjx + gjy * gjy) * area;  // jj
    M[2] = (gkx * gkx + gky * gky) * area;  // kk
    M[3] = (gix * gjx + giy * gjy) * area;  // ij
    M[4] = (gjx * gkx + gjy * gky) * area;  // jk
    M[5] = (gkx * gix + gky * giy) * area;  // ki
}

// One thread per (triangle, contribution q). q = blockIdx.y in [0,9):
// block-uniform switch, atomics straight into the dense output.
__global__ void scatter_out_kernel(const float* __restrict__ pts,
                                   const int* __restrict__ cmap,
                                   float* __restrict__ out,
                                   int T, int N) {
    int t = blockIdx.x * blockDim.x + threadIdx.x;
    if (t >= T) return;
    int q = blockIdx.y;

    int nd[3]; float M[6];
    tri_values(pts, cmap, t, nd, M);

    int row, col; float val;
    switch (q) {
        case 0: row = nd[0]; col = nd[0]; val = M[0]; break;  // ii
        case 1: row = nd[1]; col = nd[1]; val = M[1]; break;  // jj
        case 2: row = nd[2]; col = nd[2]; val = M[2]; break;  // kk
        case 3: row = nd[0]; col = nd[1]; val = M[3]; break;  // ij
        case 4: row = nd[1]; col = nd[0]; val = M[3]; break;  // ji
        case 5: row = nd[1]; col = nd[2]; val = M[4]; break;  // jk
        case 6: row = nd[2]; col = nd[1]; val = M[4]; break;  // kj
        case 7: row = nd[2]; col = nd[0]; val = M[5]; break;  // ki
        default: row = nd[0]; col = nd[2]; val = M[5]; break; // ik
    }

    atomicAdd(&out[(size_t)row * N + col], -val);
}

extern "C" void kernel_launch(void* const* d_in, const int* in_sizes, int n_in,
                              void* d_out, int out_size, void* d_ws, size_t ws_size,
                              hipStream_t stream) {
    const float* pts = (const float*)d_in[0];   // (N, 2) float32
    const int* cmap = (const int*)d_in[1];      // (T, 3) int
    int N = in_sizes[0] / 2;                    // 9216 nodes
    int T = in_sizes[1] / 3;                    // 18050 triangles
    float* out = (float*)d_out;

    size_t nvec = ((size_t)N * N) >> 2;         // 21,233,664 f32x4 vectors
    zero_kernel<<<1536, 256, 0, stream>>>(out, nvec);

    dim3 sgrid((T + 255) / 256, 9);
    scatter_out_kernel<<<sgrid, 256, 0, stream>>>(pts, cmap, out, T, N);
}

// Round 8
// 66.340 us; speedup vs baseline: 4.8122x; 1.1387x over previous
//
#include <hip/hip_runtime.h>

// FEM stiffness matrix assembly (negated): out = -M, dense N x N (N = 9216).
//
// R8: memset-SHAPED custom zero + 9-way-parallel atomic scatter.
//
// Evidence trail:
//  - R6: nontemporal stores -> 4x read amplification (partial-line RMW at MC),
//    ~1 TB/s. Plain stores are the fast path for streaming fills on gfx950.
//  - R7: plain-store zero, 1536 blocks x 54 vec/thread stride-interleaved ->
//    only ~5.1 TB/s. The rocclr fillBufferAligned (~7 TB/s on the 1.36 GB
//    harness poison fill, real duration) uses the classic memset shape:
//    huge grid, one vector store per thread, no loop.
//  - R8 replicates that shape exactly: 82,944 blocks x 256 threads, one
//    f32x4 plain store each.

typedef float f32x4 __attribute__((ext_vector_type(4)));

__global__ void __launch_bounds__(256) zero_kernel(f32x4* __restrict__ o4,
                                                   unsigned nvec) {
    unsigned v = blockIdx.x * 256u + threadIdx.x;
    if (v < nvec) {
        o4[v] = (f32x4){0.f, 0.f, 0.f, 0.f};
    }
}

__device__ __forceinline__ void tri_values(const float* __restrict__ pts,
                                           const int* __restrict__ cmap,
                                           int t, int nd[3], float M[6]) {
    int ni = cmap[3 * t + 0];
    int nj = cmap[3 * t + 1];
    int nk = cmap[3 * t + 2];
    nd[0] = ni; nd[1] = nj; nd[2] = nk;

    float x0 = pts[2 * ni + 0], y0 = pts[2 * ni + 1];
    float x1 = pts[2 * nj + 0], y1 = pts[2 * nj + 1];
    float x2 = pts[2 * nk + 0], y2 = pts[2 * nk + 1];

    float det = (x1 - x0) * (y2 - y0) - (x2 - x0) * (y1 - y0);
    float area = 0.5f * fabsf(det);
    float inv = 1.0f / det;

    float gix = (y1 - y2) * inv, giy = (x2 - x1) * inv;
    float gjx = (y2 - y0) * inv, gjy = (x0 - x2) * inv;
    float gkx = (y0 - y1) * inv, gky = (x1 - x0) * inv;

    M[0] = (gix * gix + giy * giy) * area;  // ii
    M[1] = (gjx * gjx + gjy * gjy) * area;  // jj
    M[2] = (gkx * gkx + gky * gky) * area;  // kk
    M[3] = (gix * gjx + giy * gjy) * area;  // ij
    M[4] = (gjx * gkx + gjy * gky) * area;  // jk
    M[5] = (gkx * gix + gky * giy) * area;  // ki
}

// One thread per (triangle, contribution q). q = blockIdx.y in [0,9):
// block-uniform switch, atomics straight into the dense output.
__global__ void scatter_out_kernel(const float* __restrict__ pts,
                                   const int* __restrict__ cmap,
                                   float* __restrict__ out,
                                   int T, int N) {
    int t = blockIdx.x * blockDim.x + threadIdx.x;
    if (t >= T) return;
    int q = blockIdx.y;

    int nd[3]; float M[6];
    tri_values(pts, cmap, t, nd, M);

    int row, col; float val;
    switch (q) {
        case 0: row = nd[0]; col = nd[0]; val = M[0]; break;  // ii
        case 1: row = nd[1]; col = nd[1]; val = M[1]; break;  // jj
        case 2: row = nd[2]; col = nd[2]; val = M[2]; break;  // kk
        case 3: row = nd[0]; col = nd[1]; val = M[3]; break;  // ij
        case 4: row = nd[1]; col = nd[0]; val = M[3]; break;  // ji
        case 5: row = nd[1]; col = nd[2]; val = M[4]; break;  // jk
        case 6: row = nd[2]; col = nd[1]; val = M[4]; break;  // kj
        case 7: row = nd[2]; col = nd[0]; val = M[5]; break;  // ki
        default: row = nd[0]; col = nd[2]; val = M[5]; break; // ik
    }

    atomicAdd(&out[(size_t)row * N + col], -val);
}

extern "C" void kernel_launch(void* const* d_in, const int* in_sizes, int n_in,
                              void* d_out, int out_size, void* d_ws, size_t ws_size,
                              hipStream_t stream) {
    const float* pts = (const float*)d_in[0];   // (N, 2) float32
    const int* cmap = (const int*)d_in[1];      // (T, 3) int
    int N = in_sizes[0] / 2;                    // 9216 nodes
    int T = in_sizes[1] / 3;                    // 18050 triangles
    float* out = (float*)d_out;

    unsigned nvec = (unsigned)(((size_t)N * N) >> 2);  // 21,233,664 f32x4
    unsigned zgrid = (nvec + 255u) / 256u;             // 82,944 blocks
    zero_kernel<<<zgrid, 256, 0, stream>>>((f32x4*)out, nvec);

    dim3 sgrid((T + 255) / 256, 9);
    scatter_out_kernel<<<sgrid, 256, 0, stream>>>(pts, cmap, out, T, N);
}